// Round 15
// baseline (125.534 us; speedup 1.0000x reference)
//
#include <hip/hip_runtime.h>
#include <math.h>

#define NN 10000
#define FIN 512
#define HD 40
#define GEPS 1e-5f

#define ZI4 ((2 * NN + 2 * HD) / 4)       // 5020 int4s (cnt, cur, stats)
#define MM1_BLOCKS ((NN + 15) / 16)       // 625
#define ZERO_BLOCKS ((ZI4 + 255) / 256)   // 20
#define CVT_BLOCKS ((3 * 32 * 3 * 64 + 255) / 256)   // 72

typedef _Float16 h4 __attribute__((ext_vector_type(4)));
typedef float f4 __attribute__((ext_vector_type(4)));

// ---------------- CSR build ----------------
__global__ void k_hist(const int* __restrict__ dst, int* __restrict__ cnt, int E) {
    int e = blockIdx.x * blockDim.x + threadIdx.x;
    if (e < E) atomicAdd(&cnt[dst[e]], 1);
}

// single block, 1024 threads; 16 rows/thread (625*16 == NN exactly);
// int4 loads + int4/float4 stores; fused dis=rsqrt(deg)
__global__ __launch_bounds__(1024) void k_scan(const int* __restrict__ cnt,
                                               int* __restrict__ rowstart,
                                               float* __restrict__ dis) {
    __shared__ int lds[1024];
    const int t = threadIdx.x;
    const int start = t * 16;
    int4 c[4];
    int s = 0;
    if (start < NN) {
#pragma unroll
        for (int q = 0; q < 4; ++q) {
            c[q] = *(const int4*)(cnt + start + q * 4);
            s += c[q].x + c[q].y + c[q].z + c[q].w;
        }
    }
    lds[t] = s;
    __syncthreads();
    for (int off = 1; off < 1024; off <<= 1) {
        int v = (t >= off) ? lds[t - off] : 0;
        __syncthreads();
        lds[t] += v;
        __syncthreads();
    }
    if (start < NN) {
        int run = lds[t] - s;   // exclusive prefix
#pragma unroll
        for (int q = 0; q < 4; ++q) {
            int4 rs; float4 dv;
            rs.x = run; dv.x = rsqrtf((float)c[q].x); run += c[q].x;
            rs.y = run; dv.y = rsqrtf((float)c[q].y); run += c[q].y;
            rs.z = run; dv.z = rsqrtf((float)c[q].z); run += c[q].z;
            rs.w = run; dv.w = rsqrtf((float)c[q].w); run += c[q].w;
            *(int4*)(rowstart + start + q * 4) = rs;
            *(float4*)(dis + start + q * 4) = dv;
        }
        if (start + 16 == NN) rowstart[NN] = run;
    }
}

__global__ void k_fill(const int* __restrict__ src, const int* __restrict__ dst,
                       const int* __restrict__ rowstart, int* __restrict__ cur,
                       const float* __restrict__ dis, int2* __restrict__ csr, int E) {
    int e = blockIdx.x * blockDim.x + threadIdx.x;
    if (e >= E) return;
    int s = src[e], d = dst[e];
    int pos = rowstart[d] + atomicAdd(&cur[d], 1);
    int2 v;
    v.x = s;
    v.y = __float_as_int(dis[s] * dis[d]);
    csr[pos] = v;
}

// ---------------- h1 = x @ W1 ; side blocks: zero cnt/cur/stats + cvt W->fp16 frags ----------------
__global__ __launch_bounds__(256) void k_mm1z(const float* __restrict__ x,
                                              const float* __restrict__ W1,
                                              float* __restrict__ h1,
                                              int4* __restrict__ zbuf,
                                              const float* __restrict__ Wm,
                                              const float* __restrict__ Wd,
                                              const float* __restrict__ Wp,
                                              _Float16* __restrict__ Whf) {
    if (blockIdx.x >= MM1_BLOCKS + ZERO_BLOCKS) {   // cvtW-duty blocks
        int idx = (blockIdx.x - MM1_BLOCKS - ZERO_BLOCKS) * 256 + threadIdx.x;
        if (idx < 3 * 32 * 3 * 64) {
            int lane = idx & 63;
            int kk   = (idx >> 6) % 3;
            int ct   = ((idx >> 6) / 3) % 32;
            int z    = idx / (64 * 3 * 32);
            const float* W = (z == 0) ? Wm : (z == 1) ? Wd : Wp;
            int col = ct * 16 + (lane & 15);
            h4 v;
#pragma unroll
            for (int j = 0; j < 4; ++j) {
                int krow = kk * 16 + (lane >> 4) * 4 + j;
                v[j] = (krow < HD) ? (_Float16)W[(size_t)krow * FIN + col] : (_Float16)0.f;
            }
            *(h4*)(Whf + (size_t)idx * 4) = v;
        }
        return;
    }
    if (blockIdx.x >= MM1_BLOCKS) {       // zero-duty blocks
        int i = (blockIdx.x - MM1_BLOCKS) * 256 + threadIdx.x;
        if (i < ZI4) zbuf[i] = make_int4(0, 0, 0, 0);
        return;
    }
    __shared__ float red[256 * 41];       // 41-pad: odd stride -> conflict-free
    const int tid = threadIdx.x;
    const int r = tid & 15;
    const int kg = tid >> 4;              // 0..15, 32 k each
    const int row = blockIdx.x * 16 + r;
    const int rowc = min(row, NN - 1);
    const float4* xr = (const float4*)(x + (size_t)rowc * FIN + kg * 32);
    float acc[HD];
#pragma unroll
    for (int c = 0; c < HD; ++c) acc[c] = 0.f;
#pragma unroll 2
    for (int q = 0; q < 8; ++q) {
        float4 xv = xr[q];
        const float* wbase = W1 + (size_t)(kg * 32 + q * 4) * HD;
#pragma unroll
        for (int kk = 0; kk < 4; ++kk) {
            float xs = (kk == 0) ? xv.x : (kk == 1) ? xv.y : (kk == 2) ? xv.z : xv.w;
#pragma unroll
            for (int c4 = 0; c4 < 10; ++c4) {
                float4 wv = *(const float4*)(wbase + kk * HD + c4 * 4);
                acc[c4 * 4 + 0] = fmaf(xs, wv.x, acc[c4 * 4 + 0]);
                acc[c4 * 4 + 1] = fmaf(xs, wv.y, acc[c4 * 4 + 1]);
                acc[c4 * 4 + 2] = fmaf(xs, wv.z, acc[c4 * 4 + 2]);
                acc[c4 * 4 + 3] = fmaf(xs, wv.w, acc[c4 * 4 + 3]);
            }
        }
    }
#pragma unroll
    for (int c = 0; c < HD; ++c) red[tid * 41 + c] = acc[c];
    __syncthreads();
    if (tid < 160) {                      // 16 rows x 10 float4
        int rr = tid / 10, c4 = tid % 10;
        float o0 = 0.f, o1 = 0.f, o2 = 0.f, o3 = 0.f;
#pragma unroll
        for (int kg2 = 0; kg2 < 16; ++kg2) {
            const float* p = &red[(kg2 * 16 + rr) * 41 + c4 * 4];
            o0 += p[0]; o1 += p[1]; o2 += p[2]; o3 += p[3];
        }
        int orow = blockIdx.x * 16 + rr;
        if (orow < NN)
            *(float4*)&h1[(size_t)orow * HD + c4 * 4] = make_float4(o0, o1, o2, o3);
    }
}

// ---------------- gather1 + fused GraphNorm stats ----------------
// 2 threads per (node,c4) slot, contiguous half ranges, 8 edges in flight.
// Stats: LDS partials + 80 global atomics per block (R5/R8 pattern).
__global__ __launch_bounds__(256) void k_gather1s(const int* __restrict__ rowstart,
                                                  const int2* __restrict__ csr,
                                                  const float* __restrict__ hin,
                                                  const float* __restrict__ b1,
                                                  float* __restrict__ agg1,
                                                  float* __restrict__ stats) {
    __shared__ float4 part[256];
    __shared__ float s0[HD], s1[HD];
    const int t = threadIdx.x;
    if (t < HD) { s0[t] = 0.f; s1[t] = 0.f; }
    __syncthreads();
    const int slot = blockIdx.x * 128 + (t & 127);
    const int half = t >> 7;
    float4 acc = make_float4(0.f, 0.f, 0.f, 0.f);
    if (slot < NN * 10) {
        const int n = slot / 10, c4 = slot % 10;
        const int j0 = rowstart[n], j1 = rowstart[n + 1];
        const int mid = j0 + ((j1 - j0 + 1) >> 1);
        const int ja = half ? mid : j0;
        const int jb = half ? j1 : mid;
        for (int j = ja; j < jb; j += 8) {
            const int jm = jb - 1;
            int2 e[8];
#pragma unroll
            for (int q = 0; q < 8; ++q) e[q] = csr[min(j + q, jm)];
            float4 v[8];
#pragma unroll
            for (int q = 0; q < 8; ++q)
                v[q] = *(const float4*)&hin[(size_t)e[q].x * HD + c4 * 4];
#pragma unroll
            for (int q = 0; q < 8; ++q) {
                float cf = (j + q < jb) ? __int_as_float(e[q].y) : 0.f;
                acc.x = fmaf(v[q].x, cf, acc.x);
                acc.y = fmaf(v[q].y, cf, acc.y);
                acc.z = fmaf(v[q].z, cf, acc.z);
                acc.w = fmaf(v[q].w, cf, acc.w);
            }
        }
    }
    part[t] = acc;
    __syncthreads();
    if (half == 0 && slot < NN * 10) {
        const int c4 = slot % 10;
        float4 p2 = part[t + 128];
        acc.x += p2.x; acc.y += p2.y; acc.z += p2.z; acc.w += p2.w;
        ((float4*)agg1)[slot] = acc;
        float4 bv = ((const float4*)b1)[c4];
        float vx = acc.x + bv.x, vy = acc.y + bv.y, vz = acc.z + bv.z, vw = acc.w + bv.w;
        atomicAdd(&s0[c4 * 4 + 0], vx); atomicAdd(&s0[c4 * 4 + 1], vy);
        atomicAdd(&s0[c4 * 4 + 2], vz); atomicAdd(&s0[c4 * 4 + 3], vw);
        atomicAdd(&s1[c4 * 4 + 0], vx * vx); atomicAdd(&s1[c4 * 4 + 1], vy * vy);
        atomicAdd(&s1[c4 * 4 + 2], vz * vz); atomicAdd(&s1[c4 * 4 + 3], vw * vw);
    }
    __syncthreads();
    if (t < HD) {
        atomicAdd(&stats[t], s0[t]);
        atomicAdd(&stats[HD + t], s1[t]);
    }
}

// ---------------- fused gather2(norm+relu) + MFMA heads ----------------
__device__ __forceinline__ float activate_rt(float z, int act) {
    if (act == 0) {                    // mean: clip(exp, 1e-5, 1e6)
        return fminf(fmaxf(__expf(z), 1e-5f), 1e6f);
    } else if (act == 1) {             // disp: clip(softplus, 1e-4, 1e4)
        float sp = fmaxf(z, 0.0f) + __logf(1.0f + __expf(-fabsf(z)));
        return fminf(fmaxf(sp, 1e-4f), 1e4f);
    }
    return __fdividef(1.0f, 1.0f + __expf(-z));   // pi: sigmoid
}

// grid 625 (16 rows each, exact); block 512 = 8 waves.
// Phase A: colsc from stats. Phase B: gather aggh for 16 rows into LDS f16 [16][48]
// (320 workers: 2 per (row,c4) slot, MLP-8). Phase C: 96 jobs (z=3 x ct=32) over
// 8 waves, 3x mfma_f32_16x16x16f16 each (same verified fragment math as R13).
__global__ __launch_bounds__(512) void k_gheads(const int* __restrict__ rowstart,
                                                const int2* __restrict__ csr,
                                                const float* __restrict__ agg1,
                                                const float* __restrict__ stats,
                                                const float* __restrict__ b1,
                                                const float* __restrict__ gw,
                                                const float* __restrict__ gb,
                                                const float* __restrict__ ga,
                                                const _Float16* __restrict__ Whf,
                                                const float* __restrict__ bm,
                                                const float* __restrict__ bd,
                                                const float* __restrict__ bp,
                                                float* __restrict__ out) {
    __shared__ float csc[2 * HD];
    __shared__ float4 part[320];
    __shared__ _Float16 aggh_s[16 * 48];
    const int t = threadIdx.x;
    const int rowbase = blockIdx.x * 16;

    // Phase A: column scale/shift
    if (t < HD) {
        float m   = stats[t] * (1.0f / NN);
        float ex2 = stats[HD + t] * (1.0f / NN);
        float a   = ga[t];
        float var = ex2 - 2.0f * a * m * m + a * a * m * m;
        float sc  = gw[t] * rsqrtf(var + GEPS);
        csc[t]      = sc;
        csc[HD + t] = sc * (b1[t] - a * m) + gb[t];
    }
    __syncthreads();

    // Phase B: gather 16 rows (160 slots x 2 halves = 320 workers)
    float4 acc = make_float4(0.f, 0.f, 0.f, 0.f);
    if (t < 320) {
        const int s = (t < 160) ? t : t - 160;
        const int half = (t < 160) ? 0 : 1;
        const int row = s / 10, c4 = s % 10;
        const int n = rowbase + row;
        const int j0 = rowstart[n], j1 = rowstart[n + 1];
        const int mid = j0 + ((j1 - j0 + 1) >> 1);
        const int ja = half ? mid : j0;
        const int jb = half ? j1 : mid;
        float4 sc = ((const float4*)csc)[c4];
        float4 sh = ((const float4*)csc)[10 + c4];
        for (int j = ja; j < jb; j += 8) {
            const int jm = jb - 1;
            int2 e[8];
#pragma unroll
            for (int q = 0; q < 8; ++q) e[q] = csr[min(j + q, jm)];
            float4 v[8];
#pragma unroll
            for (int q = 0; q < 8; ++q)
                v[q] = *(const float4*)&agg1[(size_t)e[q].x * HD + c4 * 4];
#pragma unroll
            for (int q = 0; q < 8; ++q) {
                float cf = (j + q < jb) ? __int_as_float(e[q].y) : 0.f;
                v[q].x = fmaxf(fmaf(sc.x, v[q].x, sh.x), 0.f);
                v[q].y = fmaxf(fmaf(sc.y, v[q].y, sh.y), 0.f);
                v[q].z = fmaxf(fmaf(sc.z, v[q].z, sh.z), 0.f);
                v[q].w = fmaxf(fmaf(sc.w, v[q].w, sh.w), 0.f);
                acc.x = fmaf(v[q].x, cf, acc.x);
                acc.y = fmaf(v[q].y, cf, acc.y);
                acc.z = fmaf(v[q].z, cf, acc.z);
                acc.w = fmaf(v[q].w, cf, acc.w);
            }
        }
        part[t] = acc;
    }
    __syncthreads();
    if (t < 160) {
        const int row = t / 10, c4 = t % 10;
        float4 p2 = part[t + 160];
        acc.x += p2.x; acc.y += p2.y; acc.z += p2.z; acc.w += p2.w;
        h4 hv = { (_Float16)acc.x, (_Float16)acc.y, (_Float16)acc.z, (_Float16)acc.w };
        *(h4*)(aggh_s + row * 48 + c4 * 4) = hv;
        if (c4 == 0) {   // zero-pad k = 40..47
            h4 zv = { (_Float16)0.f, (_Float16)0.f, (_Float16)0.f, (_Float16)0.f };
            *(h4*)(aggh_s + row * 48 + 40) = zv;
            *(h4*)(aggh_s + row * 48 + 44) = zv;
        }
    }
    __syncthreads();

    // Phase C: MFMA heads. 96 jobs over 8 waves.
    const int lane = t & 63;
    const int wvi  = t >> 6;
    const int r16  = lane & 15;
    const int kgrp = lane >> 4;
    // B-frag (aggh): row = r16, k = kk*16 + kgrp*4 + j
    const _Float16* arow = aggh_s + r16 * 48 + kgrp * 4;
    h4 g0 = *(const h4*)(arow);
    h4 g1 = *(const h4*)(arow + 16);
    h4 g2 = *(const h4*)(arow + 32);
    const int grow = rowbase + r16;

#pragma unroll
    for (int i = 0; i < 12; ++i) {
        const int job = wvi * 12 + i;            // 0..95
        const int z = job >> 5;                  // 0..2
        const int ct = job & 31;                 // 0..31
        const float* bias = (z == 0) ? bm : (z == 1) ? bd : bp;
        const _Float16* wb = Whf + ((size_t)(z * 32 + ct) * 3) * 256 + lane * 4;
        h4 w0 = *(const h4*)(wb);
        h4 w1 = *(const h4*)(wb + 256);
        h4 w2 = *(const h4*)(wb + 512);
        f4 a = {0.f, 0.f, 0.f, 0.f};
        a = __builtin_amdgcn_mfma_f32_16x16x16f16(w0, g0, a, 0, 0, 0);
        a = __builtin_amdgcn_mfma_f32_16x16x16f16(w1, g1, a, 0, 0, 0);
        a = __builtin_amdgcn_mfma_f32_16x16x16f16(w2, g2, a, 0, 0, 0);
        const int col0 = ct * 16 + kgrp * 4;
        float4 bv = *(const float4*)&bias[col0];
        float4 ov;
        ov.x = activate_rt(a[0] + bv.x, z);
        ov.y = activate_rt(a[1] + bv.y, z);
        ov.z = activate_rt(a[2] + bv.z, z);
        ov.w = activate_rt(a[3] + bv.w, z);
        *(float4*)(out + (size_t)z * NN * FIN + (size_t)grow * FIN + col0) = ov;
    }
}

extern "C" void kernel_launch(void* const* d_in, const int* in_sizes, int n_in,
                              void* d_out, int out_size, void* d_ws, size_t ws_size,
                              hipStream_t stream) {
    const float* x   = (const float*)d_in[0];
    const int*   src = (const int*)d_in[1];
    const int*   dst = (const int*)d_in[2];
    const float* W1  = (const float*)d_in[3];
    const float* b1  = (const float*)d_in[4];
    const float* gnw = (const float*)d_in[5];
    const float* gnb = (const float*)d_in[6];
    const float* gna = (const float*)d_in[7];
    const float* Wm  = (const float*)d_in[8];
    const float* bm  = (const float*)d_in[9];
    const float* Wd  = (const float*)d_in[10];
    const float* bd  = (const float*)d_in[11];
    const float* Wp  = (const float*)d_in[12];
    const float* bp  = (const float*)d_in[13];
    const int E = in_sizes[1];

    // workspace layout: zero-region (cnt,cur,stats) is 16B-aligned by construction
    float*     ws       = (float*)d_ws;
    float*     h1       = ws;                          // NN*HD f32 (mm1 out)
    float*     agg1     = h1 + (size_t)NN * HD;        // NN*HD  (gather1 out)
    int*       cnt      = (int*)(agg1 + (size_t)NN * HD);  // NN   } zeroed (int4)
    int*       cur      = cnt + NN;                    // NN     } zeroed
    float*     stats    = (float*)(cur + NN);          // 2*HD   } zeroed
    float*     dis      = stats + 2 * HD;              // NN
    int*       rowstart = (int*)(dis + NN);            // NN+1 (+1 pad for int2 align)
    int2*      csr      = (int2*)(rowstart + NN + 2);  // E int2, 8B-aligned
    _Float16*  Whf      = (_Float16*)(csr + E);        // 3*32*3*256 f16 (144 KB)
    float*     out      = (float*)d_out;

    // mm1 + zero + cvtW fused (side blocks ride along)
    k_mm1z<<<MM1_BLOCKS + ZERO_BLOCKS + CVT_BLOCKS, 256, 0, stream>>>(
        x, W1, h1, (int4*)cnt, Wm, Wd, Wp, Whf);
    k_hist<<<(E + 255) / 256, 256, 0, stream>>>(dst, cnt, E);
    k_scan<<<1, 1024, 0, stream>>>(cnt, rowstart, dis);
    k_fill<<<(E + 255) / 256, 256, 0, stream>>>(src, dst, rowstart, cur, dis, csr, E);
    const int gblocks = (NN * 10 + 127) / 128;
    k_gather1s<<<gblocks, 256, 0, stream>>>(rowstart, csr, h1, b1, agg1, stats);
    k_gheads<<<MM1_BLOCKS, 512, 0, stream>>>(rowstart, csr, agg1, stats,
                                             b1, gnw, gnb, gna,
                                             Whf, bm, bd, bp, out);
}

// Round 16
// 119.910 us; speedup vs baseline: 1.0469x; 1.0469x over previous
//
#include <hip/hip_runtime.h>
#include <math.h>

#define NN 10000
#define FIN 512
#define HD 40
#define GEPS 1e-5f

#define ZI4 ((2 * NN + 2 * HD) / 4)       // 5020 int4s (cnt, cur, stats)
#define MM1_BLOCKS ((NN + 15) / 16)       // 625
#define ZERO_BLOCKS ((ZI4 + 255) / 256)   // 20
#define CVT_BLOCKS ((3 * 32 * 3 * 64 + 255) / 256)   // 72

typedef _Float16 h4 __attribute__((ext_vector_type(4)));
typedef float f4 __attribute__((ext_vector_type(4)));

// ---------------- zero cnt/cur/stats + cvt W->fp16 fragments ----------------
// Whf[((z*32+ct)*3+kk)*64 + lane][j] = (k<40 ? W_z[k][ct*16+(lane&15)] : 0),
// k = kk*16 + (lane>>4)*4 + j   (fragment order for mfma_f32_16x16x16f16)
__global__ __launch_bounds__(256) void k_zc(int4* __restrict__ zbuf,
                                            const float* __restrict__ Wm,
                                            const float* __restrict__ Wd,
                                            const float* __restrict__ Wp,
                                            _Float16* __restrict__ Whf) {
    if (blockIdx.x < ZERO_BLOCKS) {
        int i = blockIdx.x * 256 + threadIdx.x;
        if (i < ZI4) zbuf[i] = make_int4(0, 0, 0, 0);
        return;
    }
    int idx = (blockIdx.x - ZERO_BLOCKS) * 256 + threadIdx.x;
    if (idx < 3 * 32 * 3 * 64) {
        int lane = idx & 63;
        int kk   = (idx >> 6) % 3;
        int ct   = ((idx >> 6) / 3) % 32;
        int z    = idx / (64 * 3 * 32);
        const float* W = (z == 0) ? Wm : (z == 1) ? Wd : Wp;
        int col = ct * 16 + (lane & 15);
        h4 v;
#pragma unroll
        for (int j = 0; j < 4; ++j) {
            int krow = kk * 16 + (lane >> 4) * 4 + j;
            v[j] = (krow < HD) ? (_Float16)W[(size_t)krow * FIN + col] : (_Float16)0.f;
        }
        *(h4*)(Whf + (size_t)idx * 4) = v;
    }
}

// ---------------- fused: h1 = x @ W1 (625 blocks) + edge histogram (remaining blocks) ----------------
__global__ __launch_bounds__(256) void k_histmm1(const float* __restrict__ x,
                                                 const float* __restrict__ W1,
                                                 float* __restrict__ h1,
                                                 const int* __restrict__ dst,
                                                 int* __restrict__ cnt, int E) {
    if (blockIdx.x >= MM1_BLOCKS) {       // hist-duty blocks
        int e = (blockIdx.x - MM1_BLOCKS) * 256 + threadIdx.x;
        if (e < E) atomicAdd(&cnt[dst[e]], 1);
        return;
    }
    __shared__ float red[256 * 41];       // 41-pad: odd stride -> conflict-free
    const int tid = threadIdx.x;
    const int r = tid & 15;
    const int kg = tid >> 4;              // 0..15, 32 k each
    const int row = blockIdx.x * 16 + r;
    const int rowc = min(row, NN - 1);
    const float4* xr = (const float4*)(x + (size_t)rowc * FIN + kg * 32);
    float acc[HD];
#pragma unroll
    for (int c = 0; c < HD; ++c) acc[c] = 0.f;
#pragma unroll 2
    for (int q = 0; q < 8; ++q) {
        float4 xv = xr[q];
        const float* wbase = W1 + (size_t)(kg * 32 + q * 4) * HD;
#pragma unroll
        for (int kk = 0; kk < 4; ++kk) {
            float xs = (kk == 0) ? xv.x : (kk == 1) ? xv.y : (kk == 2) ? xv.z : xv.w;
#pragma unroll
            for (int c4 = 0; c4 < 10; ++c4) {
                float4 wv = *(const float4*)(wbase + kk * HD + c4 * 4);
                acc[c4 * 4 + 0] = fmaf(xs, wv.x, acc[c4 * 4 + 0]);
                acc[c4 * 4 + 1] = fmaf(xs, wv.y, acc[c4 * 4 + 1]);
                acc[c4 * 4 + 2] = fmaf(xs, wv.z, acc[c4 * 4 + 2]);
                acc[c4 * 4 + 3] = fmaf(xs, wv.w, acc[c4 * 4 + 3]);
            }
        }
    }
#pragma unroll
    for (int c = 0; c < HD; ++c) red[tid * 41 + c] = acc[c];
    __syncthreads();
    if (tid < 160) {                      // 16 rows x 10 float4
        int rr = tid / 10, c4 = tid % 10;
        float o0 = 0.f, o1 = 0.f, o2 = 0.f, o3 = 0.f;
#pragma unroll
        for (int kg2 = 0; kg2 < 16; ++kg2) {
            const float* p = &red[(kg2 * 16 + rr) * 41 + c4 * 4];
            o0 += p[0]; o1 += p[1]; o2 += p[2]; o3 += p[3];
        }
        int orow = blockIdx.x * 16 + rr;
        if (orow < NN)
            *(float4*)&h1[(size_t)orow * HD + c4 * 4] = make_float4(o0, o1, o2, o3);
    }
}

// single block, 1024 threads; 16 rows/thread (625*16 == NN exactly);
// int4 loads + int4/float4 stores; fused dis=rsqrt(deg)
__global__ __launch_bounds__(1024) void k_scan(const int* __restrict__ cnt,
                                               int* __restrict__ rowstart,
                                               float* __restrict__ dis) {
    __shared__ int lds[1024];
    const int t = threadIdx.x;
    const int start = t * 16;
    int4 c[4];
    int s = 0;
    if (start < NN) {
#pragma unroll
        for (int q = 0; q < 4; ++q) {
            c[q] = *(const int4*)(cnt + start + q * 4);
            s += c[q].x + c[q].y + c[q].z + c[q].w;
        }
    }
    lds[t] = s;
    __syncthreads();
    for (int off = 1; off < 1024; off <<= 1) {
        int v = (t >= off) ? lds[t - off] : 0;
        __syncthreads();
        lds[t] += v;
        __syncthreads();
    }
    if (start < NN) {
        int run = lds[t] - s;   // exclusive prefix
#pragma unroll
        for (int q = 0; q < 4; ++q) {
            int4 rs; float4 dv;
            rs.x = run; dv.x = rsqrtf((float)c[q].x); run += c[q].x;
            rs.y = run; dv.y = rsqrtf((float)c[q].y); run += c[q].y;
            rs.z = run; dv.z = rsqrtf((float)c[q].z); run += c[q].z;
            rs.w = run; dv.w = rsqrtf((float)c[q].w); run += c[q].w;
            *(int4*)(rowstart + start + q * 4) = rs;
            *(float4*)(dis + start + q * 4) = dv;
        }
        if (start + 16 == NN) rowstart[NN] = run;
    }
}

__global__ void k_fill(const int* __restrict__ src, const int* __restrict__ dst,
                       const int* __restrict__ rowstart, int* __restrict__ cur,
                       const float* __restrict__ dis, int2* __restrict__ csr, int E) {
    int e = blockIdx.x * blockDim.x + threadIdx.x;
    if (e >= E) return;
    int s = src[e], d = dst[e];
    int pos = rowstart[d] + atomicAdd(&cur[d], 1);
    int2 v;
    v.x = s;
    v.y = __float_as_int(dis[s] * dis[d]);
    csr[pos] = v;
}

// ---------------- gather1 + fused GraphNorm stats ----------------
// 2 threads per (node,c4) slot, contiguous half ranges, 8 edges in flight.
__global__ __launch_bounds__(256) void k_gather1s(const int* __restrict__ rowstart,
                                                  const int2* __restrict__ csr,
                                                  const float* __restrict__ hin,
                                                  const float* __restrict__ b1,
                                                  float* __restrict__ agg1,
                                                  float* __restrict__ stats) {
    __shared__ float4 part[256];
    __shared__ float s0[HD], s1[HD];
    const int t = threadIdx.x;
    if (t < HD) { s0[t] = 0.f; s1[t] = 0.f; }
    __syncthreads();
    const int slot = blockIdx.x * 128 + (t & 127);
    const int half = t >> 7;
    float4 acc = make_float4(0.f, 0.f, 0.f, 0.f);
    if (slot < NN * 10) {
        const int n = slot / 10, c4 = slot % 10;
        const int j0 = rowstart[n], j1 = rowstart[n + 1];
        const int mid = j0 + ((j1 - j0 + 1) >> 1);
        const int ja = half ? mid : j0;
        const int jb = half ? j1 : mid;
        for (int j = ja; j < jb; j += 8) {
            const int jm = jb - 1;
            int2 e[8];
#pragma unroll
            for (int q = 0; q < 8; ++q) e[q] = csr[min(j + q, jm)];
            float4 v[8];
#pragma unroll
            for (int q = 0; q < 8; ++q)
                v[q] = *(const float4*)&hin[(size_t)e[q].x * HD + c4 * 4];
#pragma unroll
            for (int q = 0; q < 8; ++q) {
                float cf = (j + q < jb) ? __int_as_float(e[q].y) : 0.f;
                acc.x = fmaf(v[q].x, cf, acc.x);
                acc.y = fmaf(v[q].y, cf, acc.y);
                acc.z = fmaf(v[q].z, cf, acc.z);
                acc.w = fmaf(v[q].w, cf, acc.w);
            }
        }
    }
    part[t] = acc;
    __syncthreads();
    if (half == 0 && slot < NN * 10) {
        const int c4 = slot % 10;
        float4 p2 = part[t + 128];
        acc.x += p2.x; acc.y += p2.y; acc.z += p2.z; acc.w += p2.w;
        ((float4*)agg1)[slot] = acc;
        float4 bv = ((const float4*)b1)[c4];
        float vx = acc.x + bv.x, vy = acc.y + bv.y, vz = acc.z + bv.z, vw = acc.w + bv.w;
        atomicAdd(&s0[c4 * 4 + 0], vx); atomicAdd(&s0[c4 * 4 + 1], vy);
        atomicAdd(&s0[c4 * 4 + 2], vz); atomicAdd(&s0[c4 * 4 + 3], vw);
        atomicAdd(&s1[c4 * 4 + 0], vx * vx); atomicAdd(&s1[c4 * 4 + 1], vy * vy);
        atomicAdd(&s1[c4 * 4 + 2], vz * vz); atomicAdd(&s1[c4 * 4 + 3], vw * vw);
    }
    __syncthreads();
    if (t < HD) {
        atomicAdd(&stats[t], s0[t]);
        atomicAdd(&stats[HD + t], s1[t]);
    }
}

// ---------------- gather2: colsc prologue + norm+relu+aggregate -> f16 [NN][48] ----------------
__global__ __launch_bounds__(256) void k_gather2(const int* __restrict__ rowstart,
                                                 const int2* __restrict__ csr,
                                                 const float* __restrict__ agg1,
                                                 const float* __restrict__ stats,
                                                 const float* __restrict__ b1,
                                                 const float* __restrict__ gw,
                                                 const float* __restrict__ gb,
                                                 const float* __restrict__ ga,
                                                 _Float16* __restrict__ aggout_h) {
    __shared__ float4 part[256];
    __shared__ float csc[2 * HD];
    const int t = threadIdx.x;
    if (t < HD) {
        float m   = stats[t] * (1.0f / NN);
        float ex2 = stats[HD + t] * (1.0f / NN);
        float a   = ga[t];
        float var = ex2 - 2.0f * a * m * m + a * a * m * m;
        float sc  = gw[t] * rsqrtf(var + GEPS);
        csc[t]      = sc;
        csc[HD + t] = sc * (b1[t] - a * m) + gb[t];
    }
    __syncthreads();
    const int slot = blockIdx.x * 128 + (t & 127);
    const int half = t >> 7;
    float4 acc = make_float4(0.f, 0.f, 0.f, 0.f);
    if (slot < NN * 10) {
        const int n = slot / 10, c4 = slot % 10;
        const int j0 = rowstart[n], j1 = rowstart[n + 1];
        const int mid = j0 + ((j1 - j0 + 1) >> 1);
        const int ja = half ? mid : j0;
        const int jb = half ? j1 : mid;
        float4 sc = ((const float4*)csc)[c4];
        float4 sh = ((const float4*)csc)[10 + c4];
        for (int j = ja; j < jb; j += 8) {
            const int jm = jb - 1;
            int2 e[8];
#pragma unroll
            for (int q = 0; q < 8; ++q) e[q] = csr[min(j + q, jm)];
            float4 v[8];
#pragma unroll
            for (int q = 0; q < 8; ++q)
                v[q] = *(const float4*)&agg1[(size_t)e[q].x * HD + c4 * 4];
#pragma unroll
            for (int q = 0; q < 8; ++q) {
                float cf = (j + q < jb) ? __int_as_float(e[q].y) : 0.f;
                v[q].x = fmaxf(fmaf(sc.x, v[q].x, sh.x), 0.f);
                v[q].y = fmaxf(fmaf(sc.y, v[q].y, sh.y), 0.f);
                v[q].z = fmaxf(fmaf(sc.z, v[q].z, sh.z), 0.f);
                v[q].w = fmaxf(fmaf(sc.w, v[q].w, sh.w), 0.f);
                acc.x = fmaf(v[q].x, cf, acc.x);
                acc.y = fmaf(v[q].y, cf, acc.y);
                acc.z = fmaf(v[q].z, cf, acc.z);
                acc.w = fmaf(v[q].w, cf, acc.w);
            }
        }
    }
    part[t] = acc;
    __syncthreads();
    if (half == 0 && slot < NN * 10) {
        const int n = slot / 10, c4 = slot % 10;
        float4 p2 = part[t + 128];
        acc.x += p2.x; acc.y += p2.y; acc.z += p2.z; acc.w += p2.w;
        h4 hv = { (_Float16)acc.x, (_Float16)acc.y, (_Float16)acc.z, (_Float16)acc.w };
        *(h4*)(aggout_h + (size_t)n * 48 + c4 * 4) = hv;
        if (c4 == 0) {   // zero-pad k = 40..47
            h4 zv = { (_Float16)0.f, (_Float16)0.f, (_Float16)0.f, (_Float16)0.f };
            *(h4*)(aggout_h + (size_t)n * 48 + 40) = zv;
            *(h4*)(aggout_h + (size_t)n * 48 + 44) = zv;
        }
    }
}

// ---------------- heads via MFMA ----------------
__device__ __forceinline__ float activate_rt(float z, int act) {
    if (act == 0) {                    // mean: clip(exp, 1e-5, 1e6)
        return fminf(fmaxf(__expf(z), 1e-5f), 1e6f);
    } else if (act == 1) {             // disp: clip(softplus, 1e-4, 1e4)
        float sp = fmaxf(z, 0.0f) + __logf(1.0f + __expf(-fabsf(z)));
        return fminf(fmaxf(sp, 1e-4f), 1e4f);
    }
    return __fdividef(1.0f, 1.0f + __expf(-z));   // pi: sigmoid
}

// grid (625, 1, 3); block 256 = 4 waves. Wave wv: rows [bx*16,+16) x cols [wv*128,+128)
// = 8 col-tiles of 16. Per tile: 3x mfma_f32_16x16x16f16 over padded K=48.
// W-fragment in A slot -> D reg-dim = columns -> float4 stores. (Verified R13.)
__global__ __launch_bounds__(256) void k_heads3m(const _Float16* __restrict__ agghh,
                                                 const _Float16* __restrict__ Whf,
                                                 const float* __restrict__ bm,
                                                 const float* __restrict__ bd,
                                                 const float* __restrict__ bp,
                                                 float* __restrict__ out) {
    const int z = blockIdx.z;
    const float* bias = (z == 0) ? bm : (z == 1) ? bd : bp;
    float* o = out + (size_t)z * NN * FIN;

    const int lane = threadIdx.x & 63;
    const int wv   = threadIdx.x >> 6;
    const int rowbase = blockIdx.x * 16;
    const int r16  = lane & 15;
    const int kgrp = lane >> 4;

    const _Float16* arow = agghh + (size_t)(rowbase + r16) * 48 + kgrp * 4;
    h4 g0 = *(const h4*)(arow);
    h4 g1 = *(const h4*)(arow + 16);
    h4 g2 = *(const h4*)(arow + 32);

    const int grow = rowbase + r16;
    float* orow = o + (size_t)grow * FIN;

#pragma unroll
    for (int i = 0; i < 8; ++i) {
        const int ct = wv * 8 + i;               // global col-tile 0..31
        const _Float16* wb = Whf + ((size_t)(z * 32 + ct) * 3) * 256 + lane * 4;
        h4 w0 = *(const h4*)(wb);
        h4 w1 = *(const h4*)(wb + 256);
        h4 w2 = *(const h4*)(wb + 512);
        f4 acc = {0.f, 0.f, 0.f, 0.f};
        acc = __builtin_amdgcn_mfma_f32_16x16x16f16(w0, g0, acc, 0, 0, 0);
        acc = __builtin_amdgcn_mfma_f32_16x16x16f16(w1, g1, acc, 0, 0, 0);
        acc = __builtin_amdgcn_mfma_f32_16x16x16f16(w2, g2, acc, 0, 0, 0);
        const int col0 = ct * 16 + kgrp * 4;     // 4 consecutive cols in regs
        float4 bv = *(const float4*)&bias[col0];
        float4 ov;
        ov.x = activate_rt(acc[0] + bv.x, z);
        ov.y = activate_rt(acc[1] + bv.y, z);
        ov.z = activate_rt(acc[2] + bv.z, z);
        ov.w = activate_rt(acc[3] + bv.w, z);
        *(float4*)(orow + col0) = ov;
    }
}

extern "C" void kernel_launch(void* const* d_in, const int* in_sizes, int n_in,
                              void* d_out, int out_size, void* d_ws, size_t ws_size,
                              hipStream_t stream) {
    const float* x   = (const float*)d_in[0];
    const int*   src = (const int*)d_in[1];
    const int*   dst = (const int*)d_in[2];
    const float* W1  = (const float*)d_in[3];
    const float* b1  = (const float*)d_in[4];
    const float* gnw = (const float*)d_in[5];
    const float* gnb = (const float*)d_in[6];
    const float* gna = (const float*)d_in[7];
    const float* Wm  = (const float*)d_in[8];
    const float* bm  = (const float*)d_in[9];
    const float* Wd  = (const float*)d_in[10];
    const float* bd  = (const float*)d_in[11];
    const float* Wp  = (const float*)d_in[12];
    const float* bp  = (const float*)d_in[13];
    const int E = in_sizes[1];

    // workspace layout: zero-region (cnt,cur,stats) is 16B-aligned by construction
    float*     ws       = (float*)d_ws;
    float*     h1       = ws;                          // NN*HD f32 (mm1 out; agghh f16 reuses later)
    float*     agg1     = h1 + (size_t)NN * HD;        // NN*HD  (gather1 out)
    int*       cnt      = (int*)(agg1 + (size_t)NN * HD);  // NN   } zeroed (int4)
    int*       cur      = cnt + NN;                    // NN     } zeroed
    float*     stats    = (float*)(cur + NN);          // 2*HD   } zeroed
    float*     dis      = stats + 2 * HD;              // NN
    int*       rowstart = (int*)(dis + NN);            // NN+1 (+1 pad for int2 align)
    int2*      csr      = (int2*)(rowstart + NN + 2);  // E int2, 8B-aligned
    _Float16*  Whf      = (_Float16*)(csr + E);        // 3*32*3*256 f16 (144 KB)
    _Float16*  agghh    = (_Float16*)h1;               // NN*48 f16 (reuses h1 after gather1s)
    float*     out      = (float*)d_out;

    k_zc<<<ZERO_BLOCKS + CVT_BLOCKS, 256, 0, stream>>>((int4*)cnt, Wm, Wd, Wp, Whf);
    const int histb = (E + 255) / 256;
    k_histmm1<<<MM1_BLOCKS + histb, 256, 0, stream>>>(x, W1, h1, dst, cnt, E);
    k_scan<<<1, 1024, 0, stream>>>(cnt, rowstart, dis);
    k_fill<<<(E + 255) / 256, 256, 0, stream>>>(src, dst, rowstart, cur, dis, csr, E);
    const int gblocks = (NN * 10 + 127) / 128;
    k_gather1s<<<gblocks, 256, 0, stream>>>(rowstart, csr, h1, b1, agg1, stats);
    k_gather2<<<gblocks, 256, 0, stream>>>(rowstart, csr, agg1, stats,
                                           b1, gnw, gnb, gna, agghh);
    dim3 hgrid(MM1_BLOCKS, 1, 3);
    k_heads3m<<<hgrid, 256, 0, stream>>>(agghh, Whf, bm, bd, bp, out);
}

// Round 17
// 105.344 us; speedup vs baseline: 1.1917x; 1.1383x over previous
//
#include <hip/hip_runtime.h>
#include <math.h>

#define NN 10000
#define FIN 512
#define HD 40
#define GEPS 1e-5f

#define ZI4 ((2 * NN + 2 * HD) / 4)       // 5020 int4s (cnt, cur, stats)
#define MM1_BLOCKS ((NN + 15) / 16)       // 625
#define ZERO_BLOCKS ((ZI4 + 255) / 256)   // 20
#define CVT_BLOCKS ((3 * 32 * 3 * 64 + 255) / 256)   // 72

typedef _Float16 h4 __attribute__((ext_vector_type(4)));
typedef float f4 __attribute__((ext_vector_type(4)));

// ---------------- zero cnt/cur/stats + cvt W->fp16 fragments ----------------
__global__ __launch_bounds__(256) void k_zc(int4* __restrict__ zbuf,
                                            const float* __restrict__ Wm,
                                            const float* __restrict__ Wd,
                                            const float* __restrict__ Wp,
                                            _Float16* __restrict__ Whf) {
    if (blockIdx.x < ZERO_BLOCKS) {
        int i = blockIdx.x * 256 + threadIdx.x;
        if (i < ZI4) zbuf[i] = make_int4(0, 0, 0, 0);
        return;
    }
    int idx = (blockIdx.x - ZERO_BLOCKS) * 256 + threadIdx.x;
    if (idx < 3 * 32 * 3 * 64) {
        int lane = idx & 63;
        int kk   = (idx >> 6) % 3;
        int ct   = ((idx >> 6) / 3) % 32;
        int z    = idx / (64 * 3 * 32);
        const float* W = (z == 0) ? Wm : (z == 1) ? Wd : Wp;
        int col = ct * 16 + (lane & 15);
        h4 v;
#pragma unroll
        for (int j = 0; j < 4; ++j) {
            int krow = kk * 16 + (lane >> 4) * 4 + j;
            v[j] = (krow < HD) ? (_Float16)W[(size_t)krow * FIN + col] : (_Float16)0.f;
        }
        *(h4*)(Whf + (size_t)idx * 4) = v;
    }
}

// ---------------- fused: h1 = x @ W1 (625 blocks) + edge histogram ----------------
__global__ __launch_bounds__(256) void k_histmm1(const float* __restrict__ x,
                                                 const float* __restrict__ W1,
                                                 float* __restrict__ h1,
                                                 const int* __restrict__ dst,
                                                 int* __restrict__ cnt, int E) {
    if (blockIdx.x >= MM1_BLOCKS) {       // hist-duty blocks
        int e = (blockIdx.x - MM1_BLOCKS) * 256 + threadIdx.x;
        if (e < E) atomicAdd(&cnt[dst[e]], 1);
        return;
    }
    __shared__ float red[256 * 41];       // 41-pad: odd stride -> conflict-free
    const int tid = threadIdx.x;
    const int r = tid & 15;
    const int kg = tid >> 4;              // 0..15, 32 k each
    const int row = blockIdx.x * 16 + r;
    const int rowc = min(row, NN - 1);
    const float4* xr = (const float4*)(x + (size_t)rowc * FIN + kg * 32);
    float acc[HD];
#pragma unroll
    for (int c = 0; c < HD; ++c) acc[c] = 0.f;
#pragma unroll 2
    for (int q = 0; q < 8; ++q) {
        float4 xv = xr[q];
        const float* wbase = W1 + (size_t)(kg * 32 + q * 4) * HD;
#pragma unroll
        for (int kk = 0; kk < 4; ++kk) {
            float xs = (kk == 0) ? xv.x : (kk == 1) ? xv.y : (kk == 2) ? xv.z : xv.w;
#pragma unroll
            for (int c4 = 0; c4 < 10; ++c4) {
                float4 wv = *(const float4*)(wbase + kk * HD + c4 * 4);
                acc[c4 * 4 + 0] = fmaf(xs, wv.x, acc[c4 * 4 + 0]);
                acc[c4 * 4 + 1] = fmaf(xs, wv.y, acc[c4 * 4 + 1]);
                acc[c4 * 4 + 2] = fmaf(xs, wv.z, acc[c4 * 4 + 2]);
                acc[c4 * 4 + 3] = fmaf(xs, wv.w, acc[c4 * 4 + 3]);
            }
        }
    }
#pragma unroll
    for (int c = 0; c < HD; ++c) red[tid * 41 + c] = acc[c];
    __syncthreads();
    if (tid < 160) {                      // 16 rows x 10 float4
        int rr = tid / 10, c4 = tid % 10;
        float o0 = 0.f, o1 = 0.f, o2 = 0.f, o3 = 0.f;
#pragma unroll
        for (int kg2 = 0; kg2 < 16; ++kg2) {
            const float* p = &red[(kg2 * 16 + rr) * 41 + c4 * 4];
            o0 += p[0]; o1 += p[1]; o2 += p[2]; o3 += p[3];
        }
        int orow = blockIdx.x * 16 + rr;
        if (orow < NN)
            *(float4*)&h1[(size_t)orow * HD + c4 * 4] = make_float4(o0, o1, o2, o3);
    }
}

// single block, 1024 threads; 16 rows/thread; int4 I/O; fused dis=rsqrt(deg)
__global__ __launch_bounds__(1024) void k_scan(const int* __restrict__ cnt,
                                               int* __restrict__ rowstart,
                                               float* __restrict__ dis) {
    __shared__ int lds[1024];
    const int t = threadIdx.x;
    const int start = t * 16;
    int4 c[4];
    int s = 0;
    if (start < NN) {
#pragma unroll
        for (int q = 0; q < 4; ++q) {
            c[q] = *(const int4*)(cnt + start + q * 4);
            s += c[q].x + c[q].y + c[q].z + c[q].w;
        }
    }
    lds[t] = s;
    __syncthreads();
    for (int off = 1; off < 1024; off <<= 1) {
        int v = (t >= off) ? lds[t - off] : 0;
        __syncthreads();
        lds[t] += v;
        __syncthreads();
    }
    if (start < NN) {
        int run = lds[t] - s;   // exclusive prefix
#pragma unroll
        for (int q = 0; q < 4; ++q) {
            int4 rs; float4 dv;
            rs.x = run; dv.x = rsqrtf((float)c[q].x); run += c[q].x;
            rs.y = run; dv.y = rsqrtf((float)c[q].y); run += c[q].y;
            rs.z = run; dv.z = rsqrtf((float)c[q].z); run += c[q].z;
            rs.w = run; dv.w = rsqrtf((float)c[q].w); run += c[q].w;
            *(int4*)(rowstart + start + q * 4) = rs;
            *(float4*)(dis + start + q * 4) = dv;
        }
        if (start + 16 == NN) rowstart[NN] = run;
    }
}

__global__ void k_fill(const int* __restrict__ src, const int* __restrict__ dst,
                       const int* __restrict__ rowstart, int* __restrict__ cur,
                       const float* __restrict__ dis, int2* __restrict__ csr, int E) {
    int e = blockIdx.x * blockDim.x + threadIdx.x;
    if (e >= E) return;
    int s = src[e], d = dst[e];
    int pos = rowstart[d] + atomicAdd(&cur[d], 1);
    int2 v;
    v.x = s;
    v.y = __float_as_int(dis[s] * dis[d]);
    csr[pos] = v;
}

// ---------------- gather: 4 workers per (node,c4) slot ----------------
// Each worker: contiguous quarter of the edge range, 8 independent loads in
// flight (avg 4.25 edges/quarter -> ONE latency-exposed round). LDS combine.
// !NORM: writes f32 agg. NORM: colsc prologue, relu(sc*v+sh), f16 [NN][48] out.
template <bool NORM>
__global__ __launch_bounds__(256) void k_gather4(const int* __restrict__ rowstart,
                                                 const int2* __restrict__ csr,
                                                 const float* __restrict__ hin,
                                                 const float* __restrict__ stats,
                                                 const float* __restrict__ b1,
                                                 const float* __restrict__ gw,
                                                 const float* __restrict__ gb,
                                                 const float* __restrict__ ga,
                                                 float* __restrict__ aggout_f,
                                                 _Float16* __restrict__ aggout_h) {
    __shared__ float4 part[256];
    __shared__ float csc[2 * HD];
    const int t = threadIdx.x;
    if (NORM) {
        if (t < HD) {
            float m   = stats[t] * (1.0f / NN);
            float ex2 = stats[HD + t] * (1.0f / NN);
            float a   = ga[t];
            float var = ex2 - 2.0f * a * m * m + a * a * m * m;
            float sc  = gw[t] * rsqrtf(var + GEPS);
            csc[t]      = sc;
            csc[HD + t] = sc * (b1[t] - a * m) + gb[t];
        }
        __syncthreads();
    }
    const int slot = blockIdx.x * 64 + (t & 63);
    const int qtr  = t >> 6;
    float4 acc = make_float4(0.f, 0.f, 0.f, 0.f);
    if (slot < NN * 10) {
        const int n = slot / 10, c4 = slot % 10;
        const int j0 = rowstart[n], j1 = rowstart[n + 1];
        const int len = j1 - j0;
        const int ja = j0 + ((len * qtr) >> 2);
        const int jb = j0 + ((len * (qtr + 1)) >> 2);
        float4 sc, sh;
        if (NORM) {
            sc = ((const float4*)csc)[c4];
            sh = ((const float4*)csc)[10 + c4];
        }
        for (int j = ja; j < jb; j += 8) {
            const int jm = jb - 1;
            int2 e[8];
#pragma unroll
            for (int q = 0; q < 8; ++q) e[q] = csr[min(j + q, jm)];
            float4 v[8];
#pragma unroll
            for (int q = 0; q < 8; ++q)
                v[q] = *(const float4*)&hin[(size_t)e[q].x * HD + c4 * 4];
#pragma unroll
            for (int q = 0; q < 8; ++q) {
                float cf = (j + q < jb) ? __int_as_float(e[q].y) : 0.f;
                if (NORM) {
                    v[q].x = fmaxf(fmaf(sc.x, v[q].x, sh.x), 0.f);
                    v[q].y = fmaxf(fmaf(sc.y, v[q].y, sh.y), 0.f);
                    v[q].z = fmaxf(fmaf(sc.z, v[q].z, sh.z), 0.f);
                    v[q].w = fmaxf(fmaf(sc.w, v[q].w, sh.w), 0.f);
                }
                acc.x = fmaf(v[q].x, cf, acc.x);
                acc.y = fmaf(v[q].y, cf, acc.y);
                acc.z = fmaf(v[q].z, cf, acc.z);
                acc.w = fmaf(v[q].w, cf, acc.w);
            }
        }
    }
    part[t] = acc;
    __syncthreads();
    if (qtr == 0 && slot < NN * 10) {
        const int n = slot / 10, c4 = slot % 10;
        float4 p1 = part[t + 64], p2 = part[t + 128], p3 = part[t + 192];
        acc.x += p1.x + p2.x + p3.x;
        acc.y += p1.y + p2.y + p3.y;
        acc.z += p1.z + p2.z + p3.z;
        acc.w += p1.w + p2.w + p3.w;
        if (NORM) {
            h4 hv = { (_Float16)acc.x, (_Float16)acc.y, (_Float16)acc.z, (_Float16)acc.w };
            *(h4*)(aggout_h + (size_t)n * 48 + c4 * 4) = hv;
            if (c4 == 0) {   // zero-pad k = 40..47
                h4 zv = { (_Float16)0.f, (_Float16)0.f, (_Float16)0.f, (_Float16)0.f };
                *(h4*)(aggout_h + (size_t)n * 48 + 40) = zv;
                *(h4*)(aggout_h + (size_t)n * 48 + 44) = zv;
            }
        } else {
            ((float4*)aggout_f)[slot] = acc;
        }
    }
}

// ---------------- GraphNorm stats over agg1 (80 blocks, c4-constant stride) ----------------
__global__ __launch_bounds__(256) void k_stats(const float* __restrict__ agg1,
                                               const float* __restrict__ b1,
                                               float* __restrict__ stats) {
    __shared__ float s0[HD], s1[HD];
    if (threadIdx.x < HD) { s0[threadIdx.x] = 0.f; s1[threadIdx.x] = 0.f; }
    __syncthreads();
    const int gid = blockIdx.x * 256 + threadIdx.x;
    const int c4 = gid % 10;          // stride 20480 % 10 == 0 -> constant per thread
    float4 bv = ((const float4*)b1)[c4];
    float4 a0 = make_float4(0.f, 0.f, 0.f, 0.f);
    float4 a1 = a0;
    for (int i4 = gid; i4 < NN * 10; i4 += 80 * 256) {
        float4 v = ((const float4*)agg1)[i4];
        v.x += bv.x; v.y += bv.y; v.z += bv.z; v.w += bv.w;
        a0.x += v.x; a0.y += v.y; a0.z += v.z; a0.w += v.w;
        a1.x = fmaf(v.x, v.x, a1.x);
        a1.y = fmaf(v.y, v.y, a1.y);
        a1.z = fmaf(v.z, v.z, a1.z);
        a1.w = fmaf(v.w, v.w, a1.w);
    }
    atomicAdd(&s0[c4 * 4 + 0], a0.x); atomicAdd(&s0[c4 * 4 + 1], a0.y);
    atomicAdd(&s0[c4 * 4 + 2], a0.z); atomicAdd(&s0[c4 * 4 + 3], a0.w);
    atomicAdd(&s1[c4 * 4 + 0], a1.x); atomicAdd(&s1[c4 * 4 + 1], a1.y);
    atomicAdd(&s1[c4 * 4 + 2], a1.z); atomicAdd(&s1[c4 * 4 + 3], a1.w);
    __syncthreads();
    if (threadIdx.x < HD) {
        atomicAdd(&stats[threadIdx.x], s0[threadIdx.x]);
        atomicAdd(&stats[HD + threadIdx.x], s1[threadIdx.x]);
    }
}

// ---------------- heads via MFMA (verified R13) ----------------
__device__ __forceinline__ float activate_rt(float z, int act) {
    if (act == 0) {                    // mean: clip(exp, 1e-5, 1e6)
        return fminf(fmaxf(__expf(z), 1e-5f), 1e6f);
    } else if (act == 1) {             // disp: clip(softplus, 1e-4, 1e4)
        float sp = fmaxf(z, 0.0f) + __logf(1.0f + __expf(-fabsf(z)));
        return fminf(fmaxf(sp, 1e-4f), 1e4f);
    }
    return __fdividef(1.0f, 1.0f + __expf(-z));   // pi: sigmoid
}

__global__ __launch_bounds__(256) void k_heads3m(const _Float16* __restrict__ agghh,
                                                 const _Float16* __restrict__ Whf,
                                                 const float* __restrict__ bm,
                                                 const float* __restrict__ bd,
                                                 const float* __restrict__ bp,
                                                 float* __restrict__ out) {
    const int z = blockIdx.z;
    const float* bias = (z == 0) ? bm : (z == 1) ? bd : bp;
    float* o = out + (size_t)z * NN * FIN;

    const int lane = threadIdx.x & 63;
    const int wv   = threadIdx.x >> 6;
    const int rowbase = blockIdx.x * 16;
    const int r16  = lane & 15;
    const int kgrp = lane >> 4;

    const _Float16* arow = agghh + (size_t)(rowbase + r16) * 48 + kgrp * 4;
    h4 g0 = *(const h4*)(arow);
    h4 g1 = *(const h4*)(arow + 16);
    h4 g2 = *(const h4*)(arow + 32);

    const int grow = rowbase + r16;
    float* orow = o + (size_t)grow * FIN;

#pragma unroll
    for (int i = 0; i < 8; ++i) {
        const int ct = wv * 8 + i;               // global col-tile 0..31
        const _Float16* wb = Whf + ((size_t)(z * 32 + ct) * 3) * 256 + lane * 4;
        h4 w0 = *(const h4*)(wb);
        h4 w1 = *(const h4*)(wb + 256);
        h4 w2 = *(const h4*)(wb + 512);
        f4 acc = {0.f, 0.f, 0.f, 0.f};
        acc = __builtin_amdgcn_mfma_f32_16x16x16f16(w0, g0, acc, 0, 0, 0);
        acc = __builtin_amdgcn_mfma_f32_16x16x16f16(w1, g1, acc, 0, 0, 0);
        acc = __builtin_amdgcn_mfma_f32_16x16x16f16(w2, g2, acc, 0, 0, 0);
        const int col0 = ct * 16 + kgrp * 4;     // 4 consecutive cols in regs
        float4 bv = *(const float4*)&bias[col0];
        float4 ov;
        ov.x = activate_rt(acc[0] + bv.x, z);
        ov.y = activate_rt(acc[1] + bv.y, z);
        ov.z = activate_rt(acc[2] + bv.z, z);
        ov.w = activate_rt(acc[3] + bv.w, z);
        *(float4*)(orow + col0) = ov;
    }
}

extern "C" void kernel_launch(void* const* d_in, const int* in_sizes, int n_in,
                              void* d_out, int out_size, void* d_ws, size_t ws_size,
                              hipStream_t stream) {
    const float* x   = (const float*)d_in[0];
    const int*   src = (const int*)d_in[1];
    const int*   dst = (const int*)d_in[2];
    const float* W1  = (const float*)d_in[3];
    const float* b1  = (const float*)d_in[4];
    const float* gnw = (const float*)d_in[5];
    const float* gnb = (const float*)d_in[6];
    const float* gna = (const float*)d_in[7];
    const float* Wm  = (const float*)d_in[8];
    const float* bm  = (const float*)d_in[9];
    const float* Wd  = (const float*)d_in[10];
    const float* bd  = (const float*)d_in[11];
    const float* Wp  = (const float*)d_in[12];
    const float* bp  = (const float*)d_in[13];
    const int E = in_sizes[1];

    // workspace layout: zero-region (cnt,cur,stats) is 16B-aligned by construction
    float*     ws       = (float*)d_ws;
    float*     h1       = ws;                          // NN*HD f32 (mm1 out; agghh f16 reuses later)
    float*     agg1     = h1 + (size_t)NN * HD;        // NN*HD  (gather1 out)
    int*       cnt      = (int*)(agg1 + (size_t)NN * HD);  // NN   } zeroed (int4)
    int*       cur      = cnt + NN;                    // NN     } zeroed
    float*     stats    = (float*)(cur + NN);          // 2*HD   } zeroed
    float*     dis      = stats + 2 * HD;              // NN
    int*       rowstart = (int*)(dis + NN);            // NN+1 (+1 pad for int2 align)
    int2*      csr      = (int2*)(rowstart + NN + 2);  // E int2, 8B-aligned
    _Float16*  Whf      = (_Float16*)(csr + E);        // 3*32*3*256 f16 (144 KB)
    _Float16*  agghh    = (_Float16*)h1;               // NN*48 f16 (reuses h1 after gather1)
    float*     out      = (float*)d_out;

    k_zc<<<ZERO_BLOCKS + CVT_BLOCKS, 256, 0, stream>>>((int4*)cnt, Wm, Wd, Wp, Whf);
    const int histb = (E + 255) / 256;
    k_histmm1<<<MM1_BLOCKS + histb, 256, 0, stream>>>(x, W1, h1, dst, cnt, E);
    k_scan<<<1, 1024, 0, stream>>>(cnt, rowstart, dis);
    k_fill<<<(E + 255) / 256, 256, 0, stream>>>(src, dst, rowstart, cur, dis, csr, E);
    const int gblocks4 = (NN * 10 + 63) / 64;
    k_gather4<false><<<gblocks4, 256, 0, stream>>>(rowstart, csr, h1, nullptr,
                                                   nullptr, nullptr, nullptr, nullptr,
                                                   agg1, nullptr);
    k_stats<<<80, 256, 0, stream>>>(agg1, b1, stats);
    k_gather4<true><<<gblocks4, 256, 0, stream>>>(rowstart, csr, agg1, stats,
                                                  b1, gnw, gnb, gna,
                                                  nullptr, agghh);
    dim3 hgrid(MM1_BLOCKS, 1, 3);
    k_heads3m<<<hgrid, 256, 0, stream>>>(agghh, Whf, bm, bd, bp, out);
}